// Round 7
// baseline (240.687 us; speedup 1.0000x reference)
//
#include <hip/hip_runtime.h>
#include <hip/hip_bf16.h>

#define NN 50000
#define EE 800000
#define FF 128
#define HH 128
#define HID2 64
#define TT 8
#define GG 64
#define NB 196          // buckets of 256 dst nodes (NN < 196*256; NN < 2^16)
#define NSB 256         // scatter blocks
#define EPB (EE / NSB)  // 3125 edges per scatter block
#define QBLK 782        // aggr blocks per feature-quarter (782*64 = 50048 >= NN)
#define SLAB ((size_t)NN * 4)   // uint4s per feature-quarter slab (3.2 MB)

__device__ inline unsigned short f2bf(float f) {
    union { float f; unsigned u; } v; v.f = f;
    unsigned r = v.u + 0x7fff + ((v.u >> 16) & 1);  // RNE
    return (unsigned short)(r >> 16);
}

// ---- KB1: per-(scatter-block, bucket) edge counts (LDS hist) --------------
__global__ __launch_bounds__(256) void kb1(const int* __restrict__ dst,
                                           int* __restrict__ table) {
    __shared__ int cnt[NB];
    int t = threadIdx.x, blk = blockIdx.x;
    for (int i = t; i < NB; i += 256) cnt[i] = 0;
    __syncthreads();
    int e0 = blk * EPB;
    for (int e = e0 + t; e < e0 + EPB; e += 256)
        atomicAdd(&cnt[dst[e] >> 8], 1);
    __syncthreads();
    for (int i = t; i < NB; i += 256) table[blk * NB + i] = cnt[i];
}

// ---- KB2: exact scan of table -> scatter offsets; bucket bases ------------
__global__ __launch_bounds__(256) void kb2(int* __restrict__ table,
                                           int* __restrict__ bbase) {
    __shared__ int s[256];
    int b = threadIdx.x;
    int tot = 0;
    if (b < NB)
        for (int blk = 0; blk < NSB; blk++) tot += table[blk * NB + b];
    s[b] = (b < NB) ? tot : 0;
    __syncthreads();
    for (int off = 1; off < 256; off <<= 1) {
        int a = s[b];
        int w = (b >= off) ? s[b - off] : 0;
        __syncthreads();
        s[b] = a + w;
        __syncthreads();
    }
    int base = (b == 0) ? 0 : s[b - 1];
    if (b < NB) {
        bbase[b] = base;
        int run = base;
        for (int blk = 0; blk < NSB; blk++) {
            int v = table[blk * NB + b];
            table[blk * NB + b] = run;
            run += v;
        }
    }
    if (b == 0) bbase[NB] = EE;
}

// ---- KB3: scatter edges into bucket order (packed dst<<16|src) ------------
__global__ __launch_bounds__(256) void kb3(const int* __restrict__ src,
                                           const int* __restrict__ dst,
                                           const int* __restrict__ table,
                                           unsigned* __restrict__ etmp) {
    __shared__ int ofs[NB];
    __shared__ int cur[NB];
    int t = threadIdx.x, blk = blockIdx.x;
    for (int i = t; i < NB; i += 256) { ofs[i] = table[blk * NB + i]; cur[i] = 0; }
    __syncthreads();
    int e0 = blk * EPB;
    for (int e = e0 + t; e < e0 + EPB; e += 256) {
        int d = dst[e];
        int b = d >> 8;
        int r = atomicAdd(&cur[b], 1);
        etmp[ofs[b] + r] = ((unsigned)d << 16) | (unsigned)src[e];
    }
}

// ---- K_CSR: per-bucket  hist -> scan -> row_ptr/dinv -> CSR fill ----------
__global__ __launch_bounds__(256) void k_csr(const unsigned* __restrict__ etmp,
                                             const int* __restrict__ bbase,
                                             int* __restrict__ row_ptr,
                                             float* __restrict__ dinv,
                                             int* __restrict__ srcs) {
    __shared__ int s[256];
    __shared__ int cur[256];
    int t = threadIdx.x, b = blockIdx.x;
    s[t] = 0;
    __syncthreads();
    int e0 = bbase[b], e1 = bbase[b + 1];
    for (int e = e0 + t; e < e1; e += 256)
        atomicAdd(&s[(etmp[e] >> 16) & 255], 1);
    __syncthreads();
    int v = s[t];
    for (int off = 1; off < 256; off <<= 1) {
        int a = s[t];
        int w = (t >= off) ? s[t - off] : 0;
        __syncthreads();
        s[t] = a + w;
        __syncthreads();
    }
    int excl = s[t] - v + e0;   // e0 == bbase[b] == row_ptr[b*256]
    int node = b * 256 + t;
    if (node < NN) {
        row_ptr[node] = excl;
        dinv[node] = rsqrtf((float)(v + 1));  // +1 self-loop
    }
    if (b == NB - 1 && t == 0) row_ptr[NN] = EE;
    cur[t] = excl;
    __syncthreads();
    for (int e = e0 + t; e < e1; e += 256) {
        unsigned u = etmp[e];
        int slot = atomicAdd(&cur[(u >> 16) & 255], 1);
        srcs[slot] = (int)(u & 0xffffu);
    }
}

// ---------------- K4: hsq = bf16( (x @ W) * dinv[row] ), slab layout -------
// Slab q holds feature cols [q*32, q*32+32) of all rows: hsq4[q*SLAB + r*4 + j]
__global__ __launch_bounds__(256) void k_gemm(const float* __restrict__ x,
                                              const float* __restrict__ W,
                                              const float* __restrict__ dinv,
                                              uint4* __restrict__ hsq4) {
    __shared__ float xs[64 * 36];
    __shared__ float ws[32 * 132];
    int tid = threadIdx.x;
    int tx = tid & 15, ty = tid >> 4;
    int r0 = blockIdx.x * 64;
    float acc[4][8];
#pragma unroll
    for (int r = 0; r < 4; r++)
#pragma unroll
        for (int c = 0; c < 8; c++) acc[r][c] = 0.f;

    for (int k0 = 0; k0 < 128; k0 += 32) {
        {
            int row = tid >> 2, q = tid & 3;
            int gr = r0 + row;
            float4 a0 = {0, 0, 0, 0}, a1 = {0, 0, 0, 0};
            if (gr < NN) {
                const float4* p = (const float4*)(x + (size_t)gr * 128 + k0 + q * 8);
                a0 = p[0]; a1 = p[1];
            }
            float* dp = &xs[row * 36 + q * 8];
            ((float4*)dp)[0] = a0; ((float4*)dp)[1] = a1;
        }
        {
            int kr = tid >> 3, q = tid & 7;
            const float4* p = (const float4*)(W + (size_t)(k0 + kr) * 128 + q * 16);
            float4 b0 = p[0], b1 = p[1], b2 = p[2], b3 = p[3];
            float* dp = &ws[kr * 132 + q * 16];
            ((float4*)dp)[0] = b0; ((float4*)dp)[1] = b1;
            ((float4*)dp)[2] = b2; ((float4*)dp)[3] = b3;
        }
        __syncthreads();
#pragma unroll
        for (int kk = 0; kk < 32; kk++) {
            float a[4];
#pragma unroll
            for (int r = 0; r < 4; r++) a[r] = xs[(ty * 4 + r) * 36 + kk];
            float4 b0 = *(const float4*)&ws[kk * 132 + tx * 8];
            float4 b1 = *(const float4*)&ws[kk * 132 + tx * 8 + 4];
            float bv[8] = {b0.x, b0.y, b0.z, b0.w, b1.x, b1.y, b1.z, b1.w};
#pragma unroll
            for (int r = 0; r < 4; r++)
#pragma unroll
                for (int c = 0; c < 8; c++)
                    acc[r][c] = fmaf(a[r], bv[c], acc[r][c]);
        }
        __syncthreads();
    }
    int q = tx >> 2, j = tx & 3;            // this thread's 8 cols sit in quarter q
    uint4* slab = hsq4 + (size_t)q * SLAB;
#pragma unroll
    for (int r = 0; r < 4; r++) {
        int gr = r0 + ty * 4 + r;
        if (gr < NN) {
            float di = dinv[gr];
            unsigned p0 = f2bf(acc[r][0] * di) | ((unsigned)f2bf(acc[r][1] * di) << 16);
            unsigned p1 = f2bf(acc[r][2] * di) | ((unsigned)f2bf(acc[r][3] * di) << 16);
            unsigned p2 = f2bf(acc[r][4] * di) | ((unsigned)f2bf(acc[r][5] * di) << 16);
            unsigned p3 = f2bf(acc[r][6] * di) | ((unsigned)f2bf(acc[r][7] * di) << 16);
            uint4 o = {p0, p1, p2, p3};
            slab[(size_t)gr * 4 + j] = o;
        }
    }
}

// ---------------- K5: slab-local gather + bias + relu + fused pool ---------
// Quarter-major grid: blocks [q*QBLK, (q+1)*QBLK) read ONLY slab q (3.2 MB,
// fits per-XCD L2). Block covers 64 nodes; lane = (node, 16B-chunk j).
__global__ __launch_bounds__(256) void k_aggr(const uint4* __restrict__ hsq4,
                                              const int* __restrict__ row_ptr,
                                              const int* __restrict__ srcs,
                                              const float* __restrict__ dinv,
                                              const float* __restrict__ bias,
                                              const int* __restrict__ batch,
                                              float* __restrict__ gsum) {
    __shared__ float gacc[16 * 32];   // 16 group slots x 32 feats (this quarter)
    int t = threadIdx.x;
    int q = blockIdx.x / QBLK, nb = blockIdx.x % QBLK;
    int base = nb * 64;
    int node = base + (t >> 2);
    int j = t & 3;
    int lastn = base + 63; if (lastn >= NN) lastn = NN - 1;
    int g_first = batch[base];
    int gspan = batch[lastn] - g_first + 1;
    int slots = (gspan < 16) ? gspan : 16;
    for (int idx = t; idx < slots * 32; idx += 256) gacc[idx] = 0.f;
    __syncthreads();

    const uint4* slab = hsq4 + (size_t)q * SLAB;
    if (node < NN) {
        float di = dinv[node];
        uint4 su = slab[(size_t)node * 4 + j];
        float a0 = __uint_as_float(su.x << 16);
        float a1 = __uint_as_float(su.x & 0xffff0000u);
        float a2 = __uint_as_float(su.y << 16);
        float a3 = __uint_as_float(su.y & 0xffff0000u);
        float a4 = __uint_as_float(su.z << 16);
        float a5 = __uint_as_float(su.z & 0xffff0000u);
        float a6 = __uint_as_float(su.w << 16);
        float a7 = __uint_as_float(su.w & 0xffff0000u);
        int e = row_ptr[node], e1 = row_ptr[node + 1];
        for (; e + 3 < e1; e += 4) {
            int s0 = srcs[e], s1 = srcs[e + 1], s2 = srcs[e + 2], s3 = srcs[e + 3];
            uint4 u0 = slab[(size_t)s0 * 4 + j];
            uint4 u1 = slab[(size_t)s1 * 4 + j];
            uint4 u2 = slab[(size_t)s2 * 4 + j];
            uint4 u3 = slab[(size_t)s3 * 4 + j];
            a0 += __uint_as_float(u0.x << 16); a1 += __uint_as_float(u0.x & 0xffff0000u);
            a2 += __uint_as_float(u0.y << 16); a3 += __uint_as_float(u0.y & 0xffff0000u);
            a4 += __uint_as_float(u0.z << 16); a5 += __uint_as_float(u0.z & 0xffff0000u);
            a6 += __uint_as_float(u0.w << 16); a7 += __uint_as_float(u0.w & 0xffff0000u);
            a0 += __uint_as_float(u1.x << 16); a1 += __uint_as_float(u1.x & 0xffff0000u);
            a2 += __uint_as_float(u1.y << 16); a3 += __uint_as_float(u1.y & 0xffff0000u);
            a4 += __uint_as_float(u1.z << 16); a5 += __uint_as_float(u1.z & 0xffff0000u);
            a6 += __uint_as_float(u1.w << 16); a7 += __uint_as_float(u1.w & 0xffff0000u);
            a0 += __uint_as_float(u2.x << 16); a1 += __uint_as_float(u2.x & 0xffff0000u);
            a2 += __uint_as_float(u2.y << 16); a3 += __uint_as_float(u2.y & 0xffff0000u);
            a4 += __uint_as_float(u2.z << 16); a5 += __uint_as_float(u2.z & 0xffff0000u);
            a6 += __uint_as_float(u2.w << 16); a7 += __uint_as_float(u2.w & 0xffff0000u);
            a0 += __uint_as_float(u3.x << 16); a1 += __uint_as_float(u3.x & 0xffff0000u);
            a2 += __uint_as_float(u3.y << 16); a3 += __uint_as_float(u3.y & 0xffff0000u);
            a4 += __uint_as_float(u3.z << 16); a5 += __uint_as_float(u3.z & 0xffff0000u);
            a6 += __uint_as_float(u3.w << 16); a7 += __uint_as_float(u3.w & 0xffff0000u);
        }
        for (; e < e1; ++e) {
            uint4 u0 = slab[(size_t)srcs[e] * 4 + j];
            a0 += __uint_as_float(u0.x << 16); a1 += __uint_as_float(u0.x & 0xffff0000u);
            a2 += __uint_as_float(u0.y << 16); a3 += __uint_as_float(u0.y & 0xffff0000u);
            a4 += __uint_as_float(u0.z << 16); a5 += __uint_as_float(u0.z & 0xffff0000u);
            a6 += __uint_as_float(u0.w << 16); a7 += __uint_as_float(u0.w & 0xffff0000u);
        }
        const float4* b4 = (const float4*)(bias + q * 32 + j * 8);
        float4 bb0 = b4[0], bb1 = b4[1];
        float r0 = fmaxf(fmaf(a0, di, bb0.x), 0.f);
        float r1 = fmaxf(fmaf(a1, di, bb0.y), 0.f);
        float r2 = fmaxf(fmaf(a2, di, bb0.z), 0.f);
        float r3 = fmaxf(fmaf(a3, di, bb0.w), 0.f);
        float r4 = fmaxf(fmaf(a4, di, bb1.x), 0.f);
        float r5 = fmaxf(fmaf(a5, di, bb1.y), 0.f);
        float r6 = fmaxf(fmaf(a6, di, bb1.z), 0.f);
        float r7 = fmaxf(fmaf(a7, di, bb1.w), 0.f);
        int g = batch[node];
        if (gspan <= 16) {
            float* gp = &gacc[(g - g_first) * 32 + j * 8];
            atomicAdd(&gp[0], r0); atomicAdd(&gp[1], r1);
            atomicAdd(&gp[2], r2); atomicAdd(&gp[3], r3);
            atomicAdd(&gp[4], r4); atomicAdd(&gp[5], r5);
            atomicAdd(&gp[6], r6); atomicAdd(&gp[7], r7);
        } else {  // pathological span: straight to global
            float* gp = &gsum[g * 128 + q * 32 + j * 8];
            atomicAdd(&gp[0], r0); atomicAdd(&gp[1], r1);
            atomicAdd(&gp[2], r2); atomicAdd(&gp[3], r3);
            atomicAdd(&gp[4], r4); atomicAdd(&gp[5], r5);
            atomicAdd(&gp[6], r6); atomicAdd(&gp[7], r7);
        }
    }
    __syncthreads();
    if (gspan <= 16) {
        for (int idx = t; idx < slots * 32; idx += 256) {
            float v = gacc[idx];
            if (v != 0.f)
                atomicAdd(&gsum[(g_first + (idx >> 5)) * 128 + q * 32 + (idx & 31)], v);
        }
    }
}

__device__ inline int lbound(const int* __restrict__ a, int n, int key) {
    int lo = 0, hi = n;
    while (lo < hi) {
        int mid = (lo + hi) >> 1;
        if (a[mid] < key) lo = mid + 1;
        else hi = mid;
    }
    return lo;
}

// ---------------- K7: head (mean, fc1 + relu, actor softmax, critic) -------
__global__ __launch_bounds__(64) void k_head(const float* __restrict__ gsum,
                                             const int* __restrict__ batch,
                                             const float* __restrict__ fc1_w,
                                             const float* __restrict__ fc1_b,
                                             const float* __restrict__ actor_w,
                                             const float* __restrict__ actor_b,
                                             const float* __restrict__ critic_w,
                                             const float* __restrict__ critic_b,
                                             float* __restrict__ out) {
    __shared__ float gs[128];
    __shared__ float zs[64];
    __shared__ float ls[8], es[8];
    int g = blockIdx.x, t = threadIdx.x;
    int lo = lbound(batch, NN, g), hi = lbound(batch, NN, g + 1);
    float invc = 1.f / fmaxf((float)(hi - lo), 1.f);
    gs[t] = gsum[g * 128 + t] * invc;
    gs[t + 64] = gsum[g * 128 + 64 + t] * invc;
    __syncthreads();
    float z = fc1_b[t];
    for (int k = 0; k < 128; k++) z = fmaf(gs[k], fc1_w[k * 64 + t], z);
    zs[t] = fmaxf(z, 0.f);
    __syncthreads();
    if (t < 8) {
        float l = actor_b[t];
        for (int k = 0; k < 64; k++) l = fmaf(zs[k], actor_w[k * 8 + t], l);
        ls[t] = l;
    }
    __syncthreads();
    if (t < 8) {
        float m = ls[0];
#pragma unroll
        for (int j = 1; j < 8; j++) m = fmaxf(m, ls[j]);
        es[t] = expf(ls[t] - m);
    }
    __syncthreads();
    if (t < 8) {
        float ssum = 0.f;
#pragma unroll
        for (int j = 0; j < 8; j++) ssum += es[j];
        out[g * 8 + t] = es[t] / ssum;
    }
    if (t == 32) {
        float v = critic_b[0];
        for (int k = 0; k < 64; k++) v = fmaf(zs[k], critic_w[k], v);
        out[GG * TT + g] = v;
    }
}

extern "C" void kernel_launch(void* const* d_in, const int* in_sizes, int n_in,
                              void* d_out, int out_size, void* d_ws, size_t ws_size,
                              hipStream_t stream) {
    const float* x        = (const float*)d_in[0];
    const int*   ei       = (const int*)d_in[1];
    const int*   batch    = (const int*)d_in[2];
    const float* W        = (const float*)d_in[3];
    const float* b        = (const float*)d_in[4];
    const float* fc1_w    = (const float*)d_in[5];
    const float* fc1_b    = (const float*)d_in[6];
    const float* actor_w  = (const float*)d_in[7];
    const float* actor_b  = (const float*)d_in[8];
    const float* critic_w = (const float*)d_in[9];
    const float* critic_b = (const float*)d_in[10];
    float* out = (float*)d_out;

    char* ws = (char*)d_ws;
    size_t off = 0;
    uint4* hsq4      = (uint4*)(ws + off);    off += (size_t)NN * 64 * 4;  // 12.8 MB (4 slabs)
    float* dinv      = (float*)(ws + off);    off += (size_t)NN * 4;
    int*   row_ptr   = (int*)(ws + off);      off += (size_t)(NN + 1) * 4 + 12;
    int*   srcs      = (int*)(ws + off);      off += (size_t)EE * 4;       // 3.2 MB
    unsigned* etmp   = (unsigned*)(ws + off); off += (size_t)EE * 4;       // 3.2 MB
    int*   table     = (int*)(ws + off);      off += (size_t)NSB * NB * 4; // 200 KB
    int*   bbase     = (int*)(ws + off);      off += (size_t)(NB + 1) * 4;
    float* gsum      = (float*)(ws + off);    off += (size_t)GG * HH * 4;

    hipMemsetAsync(gsum, 0, (size_t)GG * HH * 4, stream);

    const int* src = ei;        // edge_index[0]
    const int* dst = ei + EE;   // edge_index[1]

    kb1<<<NSB, 256, 0, stream>>>(dst, table);
    kb2<<<1, 256, 0, stream>>>(table, bbase);
    kb3<<<NSB, 256, 0, stream>>>(src, dst, table, etmp);
    k_csr<<<NB, 256, 0, stream>>>(etmp, bbase, row_ptr, dinv, srcs);
    k_gemm<<<(NN + 63) / 64, 256, 0, stream>>>(x, W, dinv, hsq4);
    k_aggr<<<4 * QBLK, 256, 0, stream>>>(hsq4, row_ptr, srcs, dinv, b, batch, gsum);
    k_head<<<GG, 64, 0, stream>>>(gsum, batch, fc1_w, fc1_b, actor_w, actor_b,
                                  critic_w, critic_b, out);
}

// Round 8
// 216.446 us; speedup vs baseline: 1.1120x; 1.1120x over previous
//
#include <hip/hip_runtime.h>
#include <hip/hip_bf16.h>

#define NN 50000
#define EE 800000
#define FF 128
#define HH 128
#define HID2 64
#define TT 8
#define GG 64
#define NB 196          // buckets of 256 dst nodes (NN < 196*256; NN < 2^16)
#define NSB 256         // scatter blocks
#define EPB (EE / NSB)  // 3125 edges per scatter block

__device__ inline unsigned short f2bf(float f) {
    union { float f; unsigned u; } v; v.f = f;
    unsigned r = v.u + 0x7fff + ((v.u >> 16) & 1);  // RNE
    return (unsigned short)(r >> 16);
}

// ---- KB1: per-(scatter-block, bucket) edge counts (LDS hist) --------------
__global__ __launch_bounds__(256) void kb1(const int* __restrict__ dst,
                                           int* __restrict__ table) {
    __shared__ int cnt[NB];
    int t = threadIdx.x, blk = blockIdx.x;
    for (int i = t; i < NB; i += 256) cnt[i] = 0;
    __syncthreads();
    int e0 = blk * EPB;
    for (int e = e0 + t; e < e0 + EPB; e += 256)
        atomicAdd(&cnt[dst[e] >> 8], 1);
    __syncthreads();
    for (int i = t; i < NB; i += 256) table[blk * NB + i] = cnt[i];
}

// ---- KB2: exact scan of table -> scatter offsets; bucket bases ------------
__global__ __launch_bounds__(256) void kb2(int* __restrict__ table,
                                           int* __restrict__ bbase) {
    __shared__ int s[256];
    int b = threadIdx.x;
    int tot = 0;
    if (b < NB)
        for (int blk = 0; blk < NSB; blk++) tot += table[blk * NB + b];
    s[b] = (b < NB) ? tot : 0;
    __syncthreads();
    for (int off = 1; off < 256; off <<= 1) {
        int a = s[b];
        int w = (b >= off) ? s[b - off] : 0;
        __syncthreads();
        s[b] = a + w;
        __syncthreads();
    }
    int base = (b == 0) ? 0 : s[b - 1];
    if (b < NB) {
        bbase[b] = base;
        int run = base;
        for (int blk = 0; blk < NSB; blk++) {
            int v = table[blk * NB + b];
            table[blk * NB + b] = run;
            run += v;
        }
    }
    if (b == 0) bbase[NB] = EE;
}

// ---- KB3: scatter edges into bucket order (packed dst<<16|src) ------------
__global__ __launch_bounds__(256) void kb3(const int* __restrict__ src,
                                           const int* __restrict__ dst,
                                           const int* __restrict__ table,
                                           unsigned* __restrict__ etmp) {
    __shared__ int ofs[NB];
    __shared__ int cur[NB];
    int t = threadIdx.x, blk = blockIdx.x;
    for (int i = t; i < NB; i += 256) { ofs[i] = table[blk * NB + i]; cur[i] = 0; }
    __syncthreads();
    int e0 = blk * EPB;
    for (int e = e0 + t; e < e0 + EPB; e += 256) {
        int d = dst[e];
        int b = d >> 8;
        int r = atomicAdd(&cur[b], 1);
        etmp[ofs[b] + r] = ((unsigned)d << 16) | (unsigned)src[e];
    }
}

// ---- K_CSR: per-bucket  hist -> scan -> row_ptr/dinv -> CSR fill ----------
__global__ __launch_bounds__(256) void k_csr(const unsigned* __restrict__ etmp,
                                             const int* __restrict__ bbase,
                                             int* __restrict__ row_ptr,
                                             float* __restrict__ dinv,
                                             int* __restrict__ srcs) {
    __shared__ int s[256];
    __shared__ int cur[256];
    int t = threadIdx.x, b = blockIdx.x;
    s[t] = 0;
    __syncthreads();
    int e0 = bbase[b], e1 = bbase[b + 1];
    for (int e = e0 + t; e < e1; e += 256)
        atomicAdd(&s[(etmp[e] >> 16) & 255], 1);
    __syncthreads();
    int v = s[t];
    for (int off = 1; off < 256; off <<= 1) {
        int a = s[t];
        int w = (t >= off) ? s[t - off] : 0;
        __syncthreads();
        s[t] = a + w;
        __syncthreads();
    }
    int excl = s[t] - v + e0;   // e0 == bbase[b] == row_ptr[b*256]
    int node = b * 256 + t;
    if (node < NN) {
        row_ptr[node] = excl;
        dinv[node] = rsqrtf((float)(v + 1));  // +1 self-loop
    }
    if (b == NB - 1 && t == 0) row_ptr[NN] = EE;
    cur[t] = excl;
    __syncthreads();
    for (int e = e0 + t; e < e1; e += 256) {
        unsigned u = etmp[e];
        int slot = atomicAdd(&cur[(u >> 16) & 255], 1);
        srcs[slot] = (int)(u & 0xffffu);
    }
}

// ---------------- K4: hs = bf16( (x @ W) * dinv[row] )  --------------------
__global__ __launch_bounds__(256) void k_gemm(const float* __restrict__ x,
                                              const float* __restrict__ W,
                                              const float* __restrict__ dinv,
                                              unsigned* __restrict__ hs) {
    __shared__ float xs[64 * 36];
    __shared__ float ws[32 * 132];
    int tid = threadIdx.x;
    int tx = tid & 15, ty = tid >> 4;
    int r0 = blockIdx.x * 64;
    float acc[4][8];
#pragma unroll
    for (int r = 0; r < 4; r++)
#pragma unroll
        for (int c = 0; c < 8; c++) acc[r][c] = 0.f;

    for (int k0 = 0; k0 < 128; k0 += 32) {
        {
            int row = tid >> 2, q = tid & 3;
            int gr = r0 + row;
            float4 a0 = {0, 0, 0, 0}, a1 = {0, 0, 0, 0};
            if (gr < NN) {
                const float4* p = (const float4*)(x + (size_t)gr * 128 + k0 + q * 8);
                a0 = p[0]; a1 = p[1];
            }
            float* dp = &xs[row * 36 + q * 8];
            ((float4*)dp)[0] = a0; ((float4*)dp)[1] = a1;
        }
        {
            int kr = tid >> 3, q = tid & 7;
            const float4* p = (const float4*)(W + (size_t)(k0 + kr) * 128 + q * 16);
            float4 b0 = p[0], b1 = p[1], b2 = p[2], b3 = p[3];
            float* dp = &ws[kr * 132 + q * 16];
            ((float4*)dp)[0] = b0; ((float4*)dp)[1] = b1;
            ((float4*)dp)[2] = b2; ((float4*)dp)[3] = b3;
        }
        __syncthreads();
#pragma unroll
        for (int kk = 0; kk < 32; kk++) {
            float a[4];
#pragma unroll
            for (int r = 0; r < 4; r++) a[r] = xs[(ty * 4 + r) * 36 + kk];
            float4 b0 = *(const float4*)&ws[kk * 132 + tx * 8];
            float4 b1 = *(const float4*)&ws[kk * 132 + tx * 8 + 4];
            float bv[8] = {b0.x, b0.y, b0.z, b0.w, b1.x, b1.y, b1.z, b1.w};
#pragma unroll
            for (int r = 0; r < 4; r++)
#pragma unroll
                for (int c = 0; c < 8; c++)
                    acc[r][c] = fmaf(a[r], bv[c], acc[r][c]);
        }
        __syncthreads();
    }
#pragma unroll
    for (int r = 0; r < 4; r++) {
        int gr = r0 + ty * 4 + r;
        if (gr < NN) {
            float di = dinv[gr];
            unsigned p0 = f2bf(acc[r][0] * di) | ((unsigned)f2bf(acc[r][1] * di) << 16);
            unsigned p1 = f2bf(acc[r][2] * di) | ((unsigned)f2bf(acc[r][3] * di) << 16);
            unsigned p2 = f2bf(acc[r][4] * di) | ((unsigned)f2bf(acc[r][5] * di) << 16);
            unsigned p3 = f2bf(acc[r][6] * di) | ((unsigned)f2bf(acc[r][7] * di) << 16);
            uint4 o = {p0, p1, p2, p3};
            *(uint4*)(hs + (size_t)gr * 64 + tx * 4) = o;
        }
    }
}

// ---------------- K5: gather + bias + relu + fused hierarchical pool -------
// 16 quarter-waves/block, qwave = one node's 256B row (16 lanes x uint4);
// 2 nodes per qwave -> 32 nodes/block, 1563 blocks (all resident: 4KB LDS).
__global__ __launch_bounds__(256) void k_aggr(const uint4* __restrict__ hs4,
                                              const int* __restrict__ row_ptr,
                                              const int* __restrict__ srcs,
                                              const float* __restrict__ dinv,
                                              const float* __restrict__ bias,
                                              const int* __restrict__ batch,
                                              float* __restrict__ gsum) {
    __shared__ float gacc[8 * 128];   // 4 KB: 8 group slots (span>8 -> global)
    int tid = threadIdx.x;
    int qid = tid >> 4, sub = tid & 15;
    int i_base = blockIdx.x * 32;
    int g_first = batch[i_base];
    int last = i_base + 31; if (last >= NN) last = NN - 1;
    int gspan = batch[last] - g_first + 1;
    bool lds_pool = (gspan <= 8);
    int slots = lds_pool ? gspan : 0;
    for (int idx = tid; idx < slots * 128; idx += 256) gacc[idx] = 0.f;
    __syncthreads();

    const float4* b4 = (const float4*)(bias + sub * 8);
    float4 bb0 = b4[0], bb1 = b4[1];

    float racc[8];
#pragma unroll
    for (int j = 0; j < 8; j++) racc[j] = 0.f;
    int cur_lg = -1;

    for (int n = 0; n < 2; n++) {
        int i = i_base + qid * 2 + n;
        if (i >= NN) break;
        int lg = batch[i] - g_first;
        if (lg != cur_lg) {
            if (cur_lg >= 0) {
                float* gp = lds_pool ? &gacc[cur_lg * 128 + sub * 8]
                                     : &gsum[(g_first + cur_lg) * 128 + sub * 8];
#pragma unroll
                for (int j = 0; j < 8; j++) atomicAdd(&gp[j], racc[j]);
#pragma unroll
                for (int j = 0; j < 8; j++) racc[j] = 0.f;
            }
            cur_lg = lg;
        }
        float di = dinv[i];
        uint4 su = hs4[(size_t)i * 16 + sub];
        float a0 = __uint_as_float(su.x << 16);
        float a1 = __uint_as_float(su.x & 0xffff0000u);
        float a2 = __uint_as_float(su.y << 16);
        float a3 = __uint_as_float(su.y & 0xffff0000u);
        float a4 = __uint_as_float(su.z << 16);
        float a5 = __uint_as_float(su.z & 0xffff0000u);
        float a6 = __uint_as_float(su.w << 16);
        float a7 = __uint_as_float(su.w & 0xffff0000u);
        int e = row_ptr[i], e1 = row_ptr[i + 1];
        for (; e + 3 < e1; e += 4) {
            int s0 = srcs[e], s1 = srcs[e + 1], s2 = srcs[e + 2], s3 = srcs[e + 3];
            uint4 u0 = hs4[(size_t)s0 * 16 + sub];
            uint4 u1 = hs4[(size_t)s1 * 16 + sub];
            uint4 u2 = hs4[(size_t)s2 * 16 + sub];
            uint4 u3 = hs4[(size_t)s3 * 16 + sub];
            a0 += __uint_as_float(u0.x << 16); a1 += __uint_as_float(u0.x & 0xffff0000u);
            a2 += __uint_as_float(u0.y << 16); a3 += __uint_as_float(u0.y & 0xffff0000u);
            a4 += __uint_as_float(u0.z << 16); a5 += __uint_as_float(u0.z & 0xffff0000u);
            a6 += __uint_as_float(u0.w << 16); a7 += __uint_as_float(u0.w & 0xffff0000u);
            a0 += __uint_as_float(u1.x << 16); a1 += __uint_as_float(u1.x & 0xffff0000u);
            a2 += __uint_as_float(u1.y << 16); a3 += __uint_as_float(u1.y & 0xffff0000u);
            a4 += __uint_as_float(u1.z << 16); a5 += __uint_as_float(u1.z & 0xffff0000u);
            a6 += __uint_as_float(u1.w << 16); a7 += __uint_as_float(u1.w & 0xffff0000u);
            a0 += __uint_as_float(u2.x << 16); a1 += __uint_as_float(u2.x & 0xffff0000u);
            a2 += __uint_as_float(u2.y << 16); a3 += __uint_as_float(u2.y & 0xffff0000u);
            a4 += __uint_as_float(u2.z << 16); a5 += __uint_as_float(u2.z & 0xffff0000u);
            a6 += __uint_as_float(u2.w << 16); a7 += __uint_as_float(u2.w & 0xffff0000u);
            a0 += __uint_as_float(u3.x << 16); a1 += __uint_as_float(u3.x & 0xffff0000u);
            a2 += __uint_as_float(u3.y << 16); a3 += __uint_as_float(u3.y & 0xffff0000u);
            a4 += __uint_as_float(u3.z << 16); a5 += __uint_as_float(u3.z & 0xffff0000u);
            a6 += __uint_as_float(u3.w << 16); a7 += __uint_as_float(u3.w & 0xffff0000u);
        }
        for (; e < e1; ++e) {
            uint4 u0 = hs4[(size_t)srcs[e] * 16 + sub];
            a0 += __uint_as_float(u0.x << 16); a1 += __uint_as_float(u0.x & 0xffff0000u);
            a2 += __uint_as_float(u0.y << 16); a3 += __uint_as_float(u0.y & 0xffff0000u);
            a4 += __uint_as_float(u0.z << 16); a5 += __uint_as_float(u0.z & 0xffff0000u);
            a6 += __uint_as_float(u0.w << 16); a7 += __uint_as_float(u0.w & 0xffff0000u);
        }
        racc[0] += fmaxf(fmaf(a0, di, bb0.x), 0.f);
        racc[1] += fmaxf(fmaf(a1, di, bb0.y), 0.f);
        racc[2] += fmaxf(fmaf(a2, di, bb0.z), 0.f);
        racc[3] += fmaxf(fmaf(a3, di, bb0.w), 0.f);
        racc[4] += fmaxf(fmaf(a4, di, bb1.x), 0.f);
        racc[5] += fmaxf(fmaf(a5, di, bb1.y), 0.f);
        racc[6] += fmaxf(fmaf(a6, di, bb1.z), 0.f);
        racc[7] += fmaxf(fmaf(a7, di, bb1.w), 0.f);
    }
    if (cur_lg >= 0) {
        float* gp = lds_pool ? &gacc[cur_lg * 128 + sub * 8]
                             : &gsum[(g_first + cur_lg) * 128 + sub * 8];
#pragma unroll
        for (int j = 0; j < 8; j++) atomicAdd(&gp[j], racc[j]);
    }
    __syncthreads();
    for (int idx = tid; idx < slots * 128; idx += 256) {
        float v = gacc[idx];
        if (v != 0.f)
            atomicAdd(&gsum[(g_first + (idx >> 7)) * 128 + (idx & 127)], v);
    }
}

__device__ inline int lbound(const int* __restrict__ a, int n, int key) {
    int lo = 0, hi = n;
    while (lo < hi) {
        int mid = (lo + hi) >> 1;
        if (a[mid] < key) lo = mid + 1;
        else hi = mid;
    }
    return lo;
}

// ---------------- K7: head (mean, fc1 + relu, actor softmax, critic) -------
__global__ __launch_bounds__(64) void k_head(const float* __restrict__ gsum,
                                             const int* __restrict__ batch,
                                             const float* __restrict__ fc1_w,
                                             const float* __restrict__ fc1_b,
                                             const float* __restrict__ actor_w,
                                             const float* __restrict__ actor_b,
                                             const float* __restrict__ critic_w,
                                             const float* __restrict__ critic_b,
                                             float* __restrict__ out) {
    __shared__ float gs[128];
    __shared__ float zs[64];
    __shared__ float ls[8], es[8];
    int g = blockIdx.x, t = threadIdx.x;
    int lo = lbound(batch, NN, g), hi = lbound(batch, NN, g + 1);
    float invc = 1.f / fmaxf((float)(hi - lo), 1.f);
    gs[t] = gsum[g * 128 + t] * invc;
    gs[t + 64] = gsum[g * 128 + 64 + t] * invc;
    __syncthreads();
    float z = fc1_b[t];
    for (int k = 0; k < 128; k++) z = fmaf(gs[k], fc1_w[k * 64 + t], z);
    zs[t] = fmaxf(z, 0.f);
    __syncthreads();
    if (t < 8) {
        float l = actor_b[t];
        for (int k = 0; k < 64; k++) l = fmaf(zs[k], actor_w[k * 8 + t], l);
        ls[t] = l;
    }
    __syncthreads();
    if (t < 8) {
        float m = ls[0];
#pragma unroll
        for (int j = 1; j < 8; j++) m = fmaxf(m, ls[j]);
        es[t] = expf(ls[t] - m);
    }
    __syncthreads();
    if (t < 8) {
        float ssum = 0.f;
#pragma unroll
        for (int j = 0; j < 8; j++) ssum += es[j];
        out[g * 8 + t] = es[t] / ssum;
    }
    if (t == 32) {
        float v = critic_b[0];
        for (int k = 0; k < 64; k++) v = fmaf(zs[k], critic_w[k], v);
        out[GG * TT + g] = v;
    }
}

extern "C" void kernel_launch(void* const* d_in, const int* in_sizes, int n_in,
                              void* d_out, int out_size, void* d_ws, size_t ws_size,
                              hipStream_t stream) {
    const float* x        = (const float*)d_in[0];
    const int*   ei       = (const int*)d_in[1];
    const int*   batch    = (const int*)d_in[2];
    const float* W        = (const float*)d_in[3];
    const float* b        = (const float*)d_in[4];
    const float* fc1_w    = (const float*)d_in[5];
    const float* fc1_b    = (const float*)d_in[6];
    const float* actor_w  = (const float*)d_in[7];
    const float* actor_b  = (const float*)d_in[8];
    const float* critic_w = (const float*)d_in[9];
    const float* critic_b = (const float*)d_in[10];
    float* out = (float*)d_out;

    char* ws = (char*)d_ws;
    size_t off = 0;
    unsigned* hs     = (unsigned*)(ws + off); off += (size_t)NN * 64 * 4;  // 12.8 MB
    float* dinv      = (float*)(ws + off);    off += (size_t)NN * 4;
    int*   row_ptr   = (int*)(ws + off);      off += (size_t)(NN + 1) * 4 + 12;
    int*   srcs      = (int*)(ws + off);      off += (size_t)EE * 4;       // 3.2 MB
    unsigned* etmp   = (unsigned*)(ws + off); off += (size_t)EE * 4;       // 3.2 MB
    int*   table     = (int*)(ws + off);      off += (size_t)NSB * NB * 4; // 200 KB
    int*   bbase     = (int*)(ws + off);      off += (size_t)(NB + 1) * 4;
    float* gsum      = (float*)(ws + off);    off += (size_t)GG * HH * 4;

    hipMemsetAsync(gsum, 0, (size_t)GG * HH * 4, stream);

    const int* src = ei;        // edge_index[0]
    const int* dst = ei + EE;   // edge_index[1]

    kb1<<<NSB, 256, 0, stream>>>(dst, table);
    kb2<<<1, 256, 0, stream>>>(table, bbase);
    kb3<<<NSB, 256, 0, stream>>>(src, dst, table, etmp);
    k_csr<<<NB, 256, 0, stream>>>(etmp, bbase, row_ptr, dinv, srcs);
    k_gemm<<<(NN + 63) / 64, 256, 0, stream>>>(x, W, dinv, hs);
    k_aggr<<<(NN + 31) / 32, 256, 0, stream>>>((const uint4*)hs, row_ptr, srcs,
                                               dinv, b, batch, gsum);
    k_head<<<GG, 64, 0, stream>>>(gsum, batch, fc1_w, fc1_b, actor_w, actor_b,
                                  critic_w, critic_b, out);
}

// Round 9
// 199.066 us; speedup vs baseline: 1.2091x; 1.0873x over previous
//
#include <hip/hip_runtime.h>
#include <hip/hip_bf16.h>

#define NN 50000
#define EE 800000
#define FF 128
#define HH 128
#define HID2 64
#define TT 8
#define GG 64
#define NB 196          // buckets of 256 dst nodes (NN < 196*256; NN < 2^16)
#define NSB 256         // scatter blocks
#define EPB (EE / NSB)  // 3125 edges per scatter block
#define NPAD 50048      // NN padded to 64 (782 * 64)

using frag_ab = __attribute__((ext_vector_type(8))) short;  // 8 bf16
using frag_cd = __attribute__((ext_vector_type(4))) float;  // 4 fp32

__device__ inline unsigned short f2bf(float f) {
    union { float f; unsigned u; } v; v.f = f;
    unsigned r = v.u + 0x7fff + ((v.u >> 16) & 1);  // RNE
    return (unsigned short)(r >> 16);
}

// ---- KCONV: x (fp32) -> x_bf (bf16, rows padded to NPAD with zeros) -------
__global__ __launch_bounds__(256) void kconv(const float* __restrict__ x,
                                             unsigned short* __restrict__ x_bf) {
    size_t gid = (size_t)blockIdx.x * 256 + threadIdx.x;   // 1 thread = 8 elems
    size_t i8 = gid * 8;
    unsigned short o[8];
    if (i8 < (size_t)NN * 128) {
        const float4* p = (const float4*)(x + i8);
        float4 a = p[0], b = p[1];
        o[0] = f2bf(a.x); o[1] = f2bf(a.y); o[2] = f2bf(a.z); o[3] = f2bf(a.w);
        o[4] = f2bf(b.x); o[5] = f2bf(b.y); o[6] = f2bf(b.z); o[7] = f2bf(b.w);
    } else {
#pragma unroll
        for (int j = 0; j < 8; j++) o[j] = 0;
    }
    *(uint4*)(x_bf + i8) = *(const uint4*)o;
}

// ---- KWT: W[k][c] -> Wt_bf[c][k] (bf16) -----------------------------------
__global__ __launch_bounds__(256) void kwt(const float* __restrict__ W,
                                           unsigned short* __restrict__ wt_bf) {
    int gid = blockIdx.x * 256 + threadIdx.x;   // 16384 total
    int c = gid >> 7, k = gid & 127;
    wt_bf[gid] = f2bf(W[k * 128 + c]);
}

// ---- KB1: per-(scatter-block, bucket) edge counts (LDS hist) --------------
__global__ __launch_bounds__(256) void kb1(const int* __restrict__ dst,
                                           int* __restrict__ table) {
    __shared__ int cnt[NB];
    int t = threadIdx.x, blk = blockIdx.x;
    for (int i = t; i < NB; i += 256) cnt[i] = 0;
    __syncthreads();
    int e0 = blk * EPB;
    for (int e = e0 + t; e < e0 + EPB; e += 256)
        atomicAdd(&cnt[dst[e] >> 8], 1);
    __syncthreads();
    for (int i = t; i < NB; i += 256) table[blk * NB + i] = cnt[i];
}

// ---- KB2a: per-bucket column scan of table (196 blocks) -------------------
// table[blk][b] -> exclusive prefix over blk; ctot[b] = column total.
__global__ __launch_bounds__(256) void kb2a(int* __restrict__ table,
                                            int* __restrict__ ctot) {
    __shared__ int s[256];
    int t = threadIdx.x, b = blockIdx.x;
    int v = table[t * NB + b];
    s[t] = v;
    __syncthreads();
    for (int off = 1; off < 256; off <<= 1) {
        int a = s[t];
        int w = (t >= off) ? s[t - off] : 0;
        __syncthreads();
        s[t] = a + w;
        __syncthreads();
    }
    table[t * NB + b] = s[t] - v;          // exclusive within column
    if (t == 255) ctot[b] = s[255];
}

// ---- KB2b: exclusive scan of 196 column totals -> bbase -------------------
__global__ __launch_bounds__(256) void kb2b(const int* __restrict__ ctot,
                                            int* __restrict__ bbase) {
    __shared__ int s[256];
    int b = threadIdx.x;
    int v = (b < NB) ? ctot[b] : 0;
    s[b] = v;
    __syncthreads();
    for (int off = 1; off < 256; off <<= 1) {
        int a = s[b];
        int w = (b >= off) ? s[b - off] : 0;
        __syncthreads();
        s[b] = a + w;
        __syncthreads();
    }
    if (b < NB) bbase[b] = s[b] - v;
    if (b == 0) bbase[NB] = EE;
}

// ---- KB3: scatter edges into bucket order (packed dst<<16|src) ------------
__global__ __launch_bounds__(256) void kb3(const int* __restrict__ src,
                                           const int* __restrict__ dst,
                                           const int* __restrict__ table,
                                           const int* __restrict__ bbase,
                                           unsigned* __restrict__ etmp) {
    __shared__ int ofs[NB];
    __shared__ int cur[NB];
    int t = threadIdx.x, blk = blockIdx.x;
    for (int i = t; i < NB; i += 256) {
        ofs[i] = table[blk * NB + i] + bbase[i];
        cur[i] = 0;
    }
    __syncthreads();
    int e0 = blk * EPB;
    for (int e = e0 + t; e < e0 + EPB; e += 256) {
        int d = dst[e];
        int b = d >> 8;
        int r = atomicAdd(&cur[b], 1);
        etmp[ofs[b] + r] = ((unsigned)d << 16) | (unsigned)src[e];
    }
}

// ---- K_CSR: per-bucket  hist -> scan -> row_ptr/dinv -> CSR fill ----------
__global__ __launch_bounds__(256) void k_csr(const unsigned* __restrict__ etmp,
                                             const int* __restrict__ bbase,
                                             int* __restrict__ row_ptr,
                                             float* __restrict__ dinv,
                                             int* __restrict__ srcs) {
    __shared__ int s[256];
    __shared__ int cur[256];
    int t = threadIdx.x, b = blockIdx.x;
    s[t] = 0;
    __syncthreads();
    int e0 = bbase[b], e1 = bbase[b + 1];
    for (int e = e0 + t; e < e1; e += 256)
        atomicAdd(&s[(etmp[e] >> 16) & 255], 1);
    __syncthreads();
    int v = s[t];
    for (int off = 1; off < 256; off <<= 1) {
        int a = s[t];
        int w = (t >= off) ? s[t - off] : 0;
        __syncthreads();
        s[t] = a + w;
        __syncthreads();
    }
    int excl = s[t] - v + e0;   // e0 == bbase[b] == row_ptr[b*256]
    int node = b * 256 + t;
    if (node < NN) {
        row_ptr[node] = excl;
        dinv[node] = rsqrtf((float)(v + 1));  // +1 self-loop
    }
    if (b == NB - 1 && t == 0) row_ptr[NN] = EE;
    cur[t] = excl;
    __syncthreads();
    for (int e = e0 + t; e < e1; e += 256) {
        unsigned u = etmp[e];
        int slot = atomicAdd(&cur[(u >> 16) & 255], 1);
        srcs[slot] = (int)(u & 0xffffu);
    }
}

// ---- K4: MFMA GEMM  hs = bf16( (x_bf @ Wt_bf^T) * dinv[row] ) -------------
// 64 rows/block, 4 waves; wave w -> rows [r0+16w, r0+16w+16). No LDS.
// A-frag: A[m=lane&15][k=quad*8+j]; B-frag: B^T[n=lane&15][k=quad*8+j];
// C/D: col=lane&15, row=quad*4+reg  (verified layouts).
__global__ __launch_bounds__(256) void k_gemm(const unsigned short* __restrict__ x_bf,
                                              const unsigned short* __restrict__ wt_bf,
                                              const float* __restrict__ dinv,
                                              unsigned short* __restrict__ hs) {
    int tid = threadIdx.x;
    int w = tid >> 6, lane = tid & 63;
    int m = lane & 15, quad = lane >> 4;
    int r0 = blockIdx.x * 64 + w * 16;        // 782 blocks * 64 = NPAD exactly
    frag_cd acc[8];
#pragma unroll
    for (int nt = 0; nt < 8; nt++) acc[nt] = frag_cd{0.f, 0.f, 0.f, 0.f};

#pragma unroll
    for (int k0 = 0; k0 < 128; k0 += 32) {
        frag_ab a = *(const frag_ab*)(x_bf + (size_t)(r0 + m) * 128 + k0 + quad * 8);
#pragma unroll
        for (int nt = 0; nt < 8; nt++) {
            frag_ab bfr = *(const frag_ab*)(wt_bf + (size_t)(nt * 16 + m) * 128 + k0 + quad * 8);
            acc[nt] = __builtin_amdgcn_mfma_f32_16x16x32_bf16(a, bfr, acc[nt], 0, 0, 0);
        }
    }
#pragma unroll
    for (int reg = 0; reg < 4; reg++) {
        int gr = r0 + quad * 4 + reg;
        if (gr < NN) {
            float di = dinv[gr];
#pragma unroll
            for (int nt = 0; nt < 8; nt++)
                hs[(size_t)gr * 128 + nt * 16 + m] = f2bf(acc[nt][reg] * di);
        }
    }
}

// ---------------- K5: gather + bias + relu + fused hierarchical pool -------
__global__ __launch_bounds__(256) void k_aggr(const uint4* __restrict__ hs4,
                                              const int* __restrict__ row_ptr,
                                              const int* __restrict__ srcs,
                                              const float* __restrict__ dinv,
                                              const float* __restrict__ bias,
                                              const int* __restrict__ batch,
                                              float* __restrict__ gsum) {
    __shared__ float gacc[8 * 128];   // 4 KB: 8 group slots (span>8 -> global)
    int tid = threadIdx.x;
    int qid = tid >> 4, sub = tid & 15;
    int i_base = blockIdx.x * 32;
    int g_first = batch[i_base];
    int last = i_base + 31; if (last >= NN) last = NN - 1;
    int gspan = batch[last] - g_first + 1;
    bool lds_pool = (gspan <= 8);
    int slots = lds_pool ? gspan : 0;
    for (int idx = tid; idx < slots * 128; idx += 256) gacc[idx] = 0.f;
    __syncthreads();

    const float4* b4 = (const float4*)(bias + sub * 8);
    float4 bb0 = b4[0], bb1 = b4[1];

    float racc[8];
#pragma unroll
    for (int j = 0; j < 8; j++) racc[j] = 0.f;
    int cur_lg = -1;

    for (int n = 0; n < 2; n++) {
        int i = i_base + qid * 2 + n;
        if (i >= NN) break;
        int lg = batch[i] - g_first;
        if (lg != cur_lg) {
            if (cur_lg >= 0) {
                float* gp = lds_pool ? &gacc[cur_lg * 128 + sub * 8]
                                     : &gsum[(g_first + cur_lg) * 128 + sub * 8];
#pragma unroll
                for (int j = 0; j < 8; j++) atomicAdd(&gp[j], racc[j]);
#pragma unroll
                for (int j = 0; j < 8; j++) racc[j] = 0.f;
            }
            cur_lg = lg;
        }
        float di = dinv[i];
        uint4 su = hs4[(size_t)i * 16 + sub];
        float a0 = __uint_as_float(su.x << 16);
        float a1 = __uint_as_float(su.x & 0xffff0000u);
        float a2 = __uint_as_float(su.y << 16);
        float a3 = __uint_as_float(su.y & 0xffff0000u);
        float a4 = __uint_as_float(su.z << 16);
        float a5 = __uint_as_float(su.z & 0xffff0000u);
        float a6 = __uint_as_float(su.w << 16);
        float a7 = __uint_as_float(su.w & 0xffff0000u);
        int e = row_ptr[i], e1 = row_ptr[i + 1];
        for (; e + 3 < e1; e += 4) {
            int s0 = srcs[e], s1 = srcs[e + 1], s2 = srcs[e + 2], s3 = srcs[e + 3];
            uint4 u0 = hs4[(size_t)s0 * 16 + sub];
            uint4 u1 = hs4[(size_t)s1 * 16 + sub];
            uint4 u2 = hs4[(size_t)s2 * 16 + sub];
            uint4 u3 = hs4[(size_t)s3 * 16 + sub];
            a0 += __uint_as_float(u0.x << 16); a1 += __uint_as_float(u0.x & 0xffff0000u);
            a2 += __uint_as_float(u0.y << 16); a3 += __uint_as_float(u0.y & 0xffff0000u);
            a4 += __uint_as_float(u0.z << 16); a5 += __uint_as_float(u0.z & 0xffff0000u);
            a6 += __uint_as_float(u0.w << 16); a7 += __uint_as_float(u0.w & 0xffff0000u);
            a0 += __uint_as_float(u1.x << 16); a1 += __uint_as_float(u1.x & 0xffff0000u);
            a2 += __uint_as_float(u1.y << 16); a3 += __uint_as_float(u1.y & 0xffff0000u);
            a4 += __uint_as_float(u1.z << 16); a5 += __uint_as_float(u1.z & 0xffff0000u);
            a6 += __uint_as_float(u1.w << 16); a7 += __uint_as_float(u1.w & 0xffff0000u);
            a0 += __uint_as_float(u2.x << 16); a1 += __uint_as_float(u2.x & 0xffff0000u);
            a2 += __uint_as_float(u2.y << 16); a3 += __uint_as_float(u2.y & 0xffff0000u);
            a4 += __uint_as_float(u2.z << 16); a5 += __uint_as_float(u2.z & 0xffff0000u);
            a6 += __uint_as_float(u2.w << 16); a7 += __uint_as_float(u2.w & 0xffff0000u);
            a0 += __uint_as_float(u3.x << 16); a1 += __uint_as_float(u3.x & 0xffff0000u);
            a2 += __uint_as_float(u3.y << 16); a3 += __uint_as_float(u3.y & 0xffff0000u);
            a4 += __uint_as_float(u3.z << 16); a5 += __uint_as_float(u3.z & 0xffff0000u);
            a6 += __uint_as_float(u3.w << 16); a7 += __uint_as_float(u3.w & 0xffff0000u);
        }
        for (; e < e1; ++e) {
            uint4 u0 = hs4[(size_t)srcs[e] * 16 + sub];
            a0 += __uint_as_float(u0.x << 16); a1 += __uint_as_float(u0.x & 0xffff0000u);
            a2 += __uint_as_float(u0.y << 16); a3 += __uint_as_float(u0.y & 0xffff0000u);
            a4 += __uint_as_float(u0.z << 16); a5 += __uint_as_float(u0.z & 0xffff0000u);
            a6 += __uint_as_float(u0.w << 16); a7 += __uint_as_float(u0.w & 0xffff0000u);
        }
        racc[0] += fmaxf(fmaf(a0, di, bb0.x), 0.f);
        racc[1] += fmaxf(fmaf(a1, di, bb0.y), 0.f);
        racc[2] += fmaxf(fmaf(a2, di, bb0.z), 0.f);
        racc[3] += fmaxf(fmaf(a3, di, bb0.w), 0.f);
        racc[4] += fmaxf(fmaf(a4, di, bb1.x), 0.f);
        racc[5] += fmaxf(fmaf(a5, di, bb1.y), 0.f);
        racc[6] += fmaxf(fmaf(a6, di, bb1.z), 0.f);
        racc[7] += fmaxf(fmaf(a7, di, bb1.w), 0.f);
    }
    if (cur_lg >= 0) {
        float* gp = lds_pool ? &gacc[cur_lg * 128 + sub * 8]
                             : &gsum[(g_first + cur_lg) * 128 + sub * 8];
#pragma unroll
        for (int j = 0; j < 8; j++) atomicAdd(&gp[j], racc[j]);
    }
    __syncthreads();
    for (int idx = tid; idx < slots * 128; idx += 256) {
        float v = gacc[idx];
        if (v != 0.f)
            atomicAdd(&gsum[(g_first + (idx >> 7)) * 128 + (idx & 127)], v);
    }
}

__device__ inline int lbound(const int* __restrict__ a, int n, int key) {
    int lo = 0, hi = n;
    while (lo < hi) {
        int mid = (lo + hi) >> 1;
        if (a[mid] < key) lo = mid + 1;
        else hi = mid;
    }
    return lo;
}

// ---------------- K7: head (mean, fc1 + relu, actor softmax, critic) -------
__global__ __launch_bounds__(64) void k_head(const float* __restrict__ gsum,
                                             const int* __restrict__ batch,
                                             const float* __restrict__ fc1_w,
                                             const float* __restrict__ fc1_b,
                                             const float* __restrict__ actor_w,
                                             const float* __restrict__ actor_b,
                                             const float* __restrict__ critic_w,
                                             const float* __restrict__ critic_b,
                                             float* __restrict__ out) {
    __shared__ float gs[128];
    __shared__ float zs[64];
    __shared__ float ls[8], es[8];
    int g = blockIdx.x, t = threadIdx.x;
    int lo = lbound(batch, NN, g), hi = lbound(batch, NN, g + 1);
    float invc = 1.f / fmaxf((float)(hi - lo), 1.f);
    gs[t] = gsum[g * 128 + t] * invc;
    gs[t + 64] = gsum[g * 128 + 64 + t] * invc;
    __syncthreads();
    float z = fc1_b[t];
    for (int k = 0; k < 128; k++) z = fmaf(gs[k], fc1_w[k * 64 + t], z);
    zs[t] = fmaxf(z, 0.f);
    __syncthreads();
    if (t < 8) {
        float l = actor_b[t];
        for (int k = 0; k < 64; k++) l = fmaf(zs[k], actor_w[k * 8 + t], l);
        ls[t] = l;
    }
    __syncthreads();
    if (t < 8) {
        float m = ls[0];
#pragma unroll
        for (int j = 1; j < 8; j++) m = fmaxf(m, ls[j]);
        es[t] = expf(ls[t] - m);
    }
    __syncthreads();
    if (t < 8) {
        float ssum = 0.f;
#pragma unroll
        for (int j = 0; j < 8; j++) ssum += es[j];
        out[g * 8 + t] = es[t] / ssum;
    }
    if (t == 32) {
        float v = critic_b[0];
        for (int k = 0; k < 64; k++) v = fmaf(zs[k], critic_w[k], v);
        out[GG * TT + g] = v;
    }
}

extern "C" void kernel_launch(void* const* d_in, const int* in_sizes, int n_in,
                              void* d_out, int out_size, void* d_ws, size_t ws_size,
                              hipStream_t stream) {
    const float* x        = (const float*)d_in[0];
    const int*   ei       = (const int*)d_in[1];
    const int*   batch    = (const int*)d_in[2];
    const float* W        = (const float*)d_in[3];
    const float* b        = (const float*)d_in[4];
    const float* fc1_w    = (const float*)d_in[5];
    const float* fc1_b    = (const float*)d_in[6];
    const float* actor_w  = (const float*)d_in[7];
    const float* actor_b  = (const float*)d_in[8];
    const float* critic_w = (const float*)d_in[9];
    const float* critic_b = (const float*)d_in[10];
    float* out = (float*)d_out;

    char* ws = (char*)d_ws;
    size_t off = 0;
    unsigned short* hs    = (unsigned short*)(ws + off); off += (size_t)NN * 128 * 2 + 64;     // 12.8 MB
    unsigned short* x_bf  = (unsigned short*)(ws + off); off += (size_t)NPAD * 128 * 2;        // 12.8 MB
    unsigned short* wt_bf = (unsigned short*)(ws + off); off += (size_t)128 * 128 * 2;         // 32 KB
    float* dinv      = (float*)(ws + off);    off += (size_t)NN * 4;
    int*   row_ptr   = (int*)(ws + off);      off += (size_t)(NN + 1) * 4 + 12;
    int*   srcs      = (int*)(ws + off);      off += (size_t)EE * 4;       // 3.2 MB
    unsigned* etmp   = (unsigned*)(ws + off); off += (size_t)EE * 4;       // 3.2 MB
    int*   table     = (int*)(ws + off);      off += (size_t)NSB * NB * 4; // 200 KB
    int*   bbase     = (int*)(ws + off);      off += (size_t)(NB + 1) * 4 + 12;
    int*   ctot      = (int*)(ws + off);      off += (size_t)NB * 4 + 16;
    float* gsum      = (float*)(ws + off);    off += (size_t)GG * HH * 4;

    hipMemsetAsync(gsum, 0, (size_t)GG * HH * 4, stream);

    const int* src = ei;        // edge_index[0]
    const int* dst = ei + EE;   // edge_index[1]

    kconv<<<(NPAD * 128 / 8 + 255) / 256, 256, 0, stream>>>(x, x_bf);
    kwt<<<64, 256, 0, stream>>>(W, wt_bf);
    kb1<<<NSB, 256, 0, stream>>>(dst, table);
    kb2a<<<NB, 256, 0, stream>>>(table, ctot);
    kb2b<<<1, 256, 0, stream>>>(ctot, bbase);
    kb3<<<NSB, 256, 0, stream>>>(src, dst, table, bbase, etmp);
    k_csr<<<NB, 256, 0, stream>>>(etmp, bbase, row_ptr, dinv, srcs);
    k_gemm<<<NPAD / 64, 256, 0, stream>>>(x_bf, wt_bf, dinv, hs);
    k_aggr<<<(NN + 31) / 32, 256, 0, stream>>>((const uint4*)hs, row_ptr, srcs,
                                               dinv, b, batch, gsum);
    k_head<<<GG, 64, 0, stream>>>(gsum, batch, fc1_w, fc1_b, actor_w, actor_b,
                                  critic_w, critic_b, out);
}

// Round 10
// 196.025 us; speedup vs baseline: 1.2278x; 1.0155x over previous
//
#include <hip/hip_runtime.h>
#include <hip/hip_bf16.h>

#define NN 50000
#define EE 800000
#define FF 128
#define HH 128
#define HID2 64
#define TT 8
#define GG 64
#define NB 196          // buckets of 256 dst nodes (NN < 196*256; NN < 2^16)
#define NSB 256         // scatter blocks
#define EPB (EE / NSB)  // 3125 edges per scatter block
#define NPAD 50048      // NN padded to 64 (782 * 64)

using frag_ab = __attribute__((ext_vector_type(8))) short;  // 8 bf16
using frag_cd = __attribute__((ext_vector_type(4))) float;  // 4 fp32

__device__ inline unsigned short f2bf(float f) {
    union { float f; unsigned u; } v; v.f = f;
    unsigned r = v.u + 0x7fff + ((v.u >> 16) & 1);  // RNE
    return (unsigned short)(r >> 16);
}

// ---- K_FRONT: kb1 LDS histogram  +  W->Wt bf16  +  gsum zero  (1 launch) --
__global__ __launch_bounds__(256) void k_front(const int* __restrict__ dst,
                                               const float* __restrict__ W,
                                               int* __restrict__ table,
                                               unsigned short* __restrict__ wt_bf,
                                               float* __restrict__ gsum) {
    __shared__ int cnt[NB];
    int t = threadIdx.x, blk = blockIdx.x;
    // side job 1: W[k][c] -> wt_bf[c][k] (blocks 0..63)
    if (blk < 64) {
        int gid = blk * 256 + t;          // 16384 total
        int c = gid >> 7, k = gid & 127;
        wt_bf[gid] = f2bf(W[k * 128 + c]);
    }
    // side job 2: zero gsum (blocks 64..95)
    if (blk >= 64 && blk < 96) {
        int gid = (blk - 64) * 256 + t;   // 8192 floats
        gsum[gid] = 0.f;
    }
    // main job: per-(block,bucket) histogram
    for (int i = t; i < NB; i += 256) cnt[i] = 0;
    __syncthreads();
    int e0 = blk * EPB;
    for (int e = e0 + t; e < e0 + EPB; e += 256)
        atomicAdd(&cnt[dst[e] >> 8], 1);
    __syncthreads();
    for (int i = t; i < NB; i += 256) table[blk * NB + i] = cnt[i];
}

// ---- KB2a: per-bucket column scan of table (196 blocks) -------------------
__global__ __launch_bounds__(256) void kb2a(int* __restrict__ table,
                                            int* __restrict__ ctot) {
    __shared__ int s[256];
    int t = threadIdx.x, b = blockIdx.x;
    int v = table[t * NB + b];
    s[t] = v;
    __syncthreads();
    for (int off = 1; off < 256; off <<= 1) {
        int a = s[t];
        int w = (t >= off) ? s[t - off] : 0;
        __syncthreads();
        s[t] = a + w;
        __syncthreads();
    }
    table[t * NB + b] = s[t] - v;          // exclusive within column
    if (t == 255) ctot[b] = s[255];
}

// ---- KB2b: exclusive scan of 196 column totals -> bbase -------------------
__global__ __launch_bounds__(256) void kb2b(const int* __restrict__ ctot,
                                            int* __restrict__ bbase) {
    __shared__ int s[256];
    int b = threadIdx.x;
    int v = (b < NB) ? ctot[b] : 0;
    s[b] = v;
    __syncthreads();
    for (int off = 1; off < 256; off <<= 1) {
        int a = s[b];
        int w = (b >= off) ? s[b - off] : 0;
        __syncthreads();
        s[b] = a + w;
        __syncthreads();
    }
    if (b < NB) bbase[b] = s[b] - v;
    if (b == 0) bbase[NB] = EE;
}

// ---- KB3: scatter edges into bucket order (packed dst<<16|src) ------------
__global__ __launch_bounds__(256) void kb3(const int* __restrict__ src,
                                           const int* __restrict__ dst,
                                           const int* __restrict__ table,
                                           const int* __restrict__ bbase,
                                           unsigned* __restrict__ etmp) {
    __shared__ int ofs[NB];
    __shared__ int cur[NB];
    int t = threadIdx.x, blk = blockIdx.x;
    for (int i = t; i < NB; i += 256) {
        ofs[i] = table[blk * NB + i] + bbase[i];
        cur[i] = 0;
    }
    __syncthreads();
    int e0 = blk * EPB;
    for (int e = e0 + t; e < e0 + EPB; e += 256) {
        int d = dst[e];
        int b = d >> 8;
        int r = atomicAdd(&cur[b], 1);
        etmp[ofs[b] + r] = ((unsigned)d << 16) | (unsigned)src[e];
    }
}

// ---- K_CSR: per-bucket  hist -> scan -> row_ptr/dinv -> CSR fill ----------
__global__ __launch_bounds__(256) void k_csr(const unsigned* __restrict__ etmp,
                                             const int* __restrict__ bbase,
                                             int* __restrict__ row_ptr,
                                             float* __restrict__ dinv,
                                             int* __restrict__ srcs) {
    __shared__ int s[256];
    __shared__ int cur[256];
    int t = threadIdx.x, b = blockIdx.x;
    s[t] = 0;
    __syncthreads();
    int e0 = bbase[b], e1 = bbase[b + 1];
    for (int e = e0 + t; e < e1; e += 256)
        atomicAdd(&s[(etmp[e] >> 16) & 255], 1);
    __syncthreads();
    int v = s[t];
    for (int off = 1; off < 256; off <<= 1) {
        int a = s[t];
        int w = (t >= off) ? s[t - off] : 0;
        __syncthreads();
        s[t] = a + w;
        __syncthreads();
    }
    int excl = s[t] - v + e0;   // e0 == bbase[b] == row_ptr[b*256]
    int node = b * 256 + t;
    if (node < NN) {
        row_ptr[node] = excl;
        dinv[node] = rsqrtf((float)(v + 1));  // +1 self-loop
    }
    if (b == NB - 1 && t == 0) row_ptr[NN] = EE;
    cur[t] = excl;
    __syncthreads();
    for (int e = e0 + t; e < e1; e += 256) {
        unsigned u = etmp[e];
        int slot = atomicAdd(&cur[(u >> 16) & 255], 1);
        srcs[slot] = (int)(u & 0xffffu);
    }
}

// ---- K4: MFMA GEMM  hs = bf16( (x @ W) * dinv[row] ), direct fp32 x -------
// 64 rows/block, 4 waves; wave w -> rows [r0+16w, r0+16w+16). No LDS.
// A-frag: A[m=lane&15][k=quad*8+j] (converted fp32->bf16 in-register);
// B-frag: B^T[n=lane&15][k=quad*8+j]; C/D: col=lane&15, row=quad*4+reg.
__global__ __launch_bounds__(256) void k_gemm(const float* __restrict__ x,
                                              const unsigned short* __restrict__ wt_bf,
                                              const float* __restrict__ dinv,
                                              unsigned short* __restrict__ hs) {
    int tid = threadIdx.x;
    int w = tid >> 6, lane = tid & 63;
    int m = lane & 15, quad = lane >> 4;
    int r0 = blockIdx.x * 64 + w * 16;        // 782 blocks * 64 = NPAD exactly
    int row = r0 + m;
    frag_cd acc[8];
#pragma unroll
    for (int nt = 0; nt < 8; nt++) acc[nt] = frag_cd{0.f, 0.f, 0.f, 0.f};

#pragma unroll
    for (int k0 = 0; k0 < 128; k0 += 32) {
        unsigned short av[8];
        if (row < NN) {
            const float4* p = (const float4*)(x + (size_t)row * 128 + k0 + quad * 8);
            float4 a0 = p[0], a1 = p[1];
            av[0] = f2bf(a0.x); av[1] = f2bf(a0.y); av[2] = f2bf(a0.z); av[3] = f2bf(a0.w);
            av[4] = f2bf(a1.x); av[5] = f2bf(a1.y); av[6] = f2bf(a1.z); av[7] = f2bf(a1.w);
        } else {
#pragma unroll
            for (int j = 0; j < 8; j++) av[j] = 0;
        }
        frag_ab a = *(const frag_ab*)av;
#pragma unroll
        for (int nt = 0; nt < 8; nt++) {
            frag_ab bfr = *(const frag_ab*)(wt_bf + (size_t)(nt * 16 + m) * 128 + k0 + quad * 8);
            acc[nt] = __builtin_amdgcn_mfma_f32_16x16x32_bf16(a, bfr, acc[nt], 0, 0, 0);
        }
    }
#pragma unroll
    for (int reg = 0; reg < 4; reg++) {
        int gr = r0 + quad * 4 + reg;
        if (gr < NN) {
            float di = dinv[gr];
#pragma unroll
            for (int nt = 0; nt < 8; nt++)
                hs[(size_t)gr * 128 + nt * 16 + m] = f2bf(acc[nt][reg] * di);
        }
    }
}

// ---------------- K5: gather + bias + relu + fused hierarchical pool -------
// 16 quarter-waves/block; qwave = node row (16 lanes x uint4); 2 nodes/qwave.
// 8-deep load pipeline vs gather latency.
#define ACC8(u) \
    a0 += __uint_as_float((u).x << 16); a1 += __uint_as_float((u).x & 0xffff0000u); \
    a2 += __uint_as_float((u).y << 16); a3 += __uint_as_float((u).y & 0xffff0000u); \
    a4 += __uint_as_float((u).z << 16); a5 += __uint_as_float((u).z & 0xffff0000u); \
    a6 += __uint_as_float((u).w << 16); a7 += __uint_as_float((u).w & 0xffff0000u);

__global__ __launch_bounds__(256) void k_aggr(const uint4* __restrict__ hs4,
                                              const int* __restrict__ row_ptr,
                                              const int* __restrict__ srcs,
                                              const float* __restrict__ dinv,
                                              const float* __restrict__ bias,
                                              const int* __restrict__ batch,
                                              float* __restrict__ gsum) {
    __shared__ float gacc[8 * 128];   // 4 KB: 8 group slots (span>8 -> global)
    int tid = threadIdx.x;
    int qid = tid >> 4, sub = tid & 15;
    int i_base = blockIdx.x * 32;
    int g_first = batch[i_base];
    int last = i_base + 31; if (last >= NN) last = NN - 1;
    int gspan = batch[last] - g_first + 1;
    bool lds_pool = (gspan <= 8);
    int slots = lds_pool ? gspan : 0;
    for (int idx = tid; idx < slots * 128; idx += 256) gacc[idx] = 0.f;
    __syncthreads();

    const float4* b4 = (const float4*)(bias + sub * 8);
    float4 bb0 = b4[0], bb1 = b4[1];

    float racc[8];
#pragma unroll
    for (int j = 0; j < 8; j++) racc[j] = 0.f;
    int cur_lg = -1;

    for (int n = 0; n < 2; n++) {
        int i = i_base + qid * 2 + n;
        if (i >= NN) break;
        int lg = batch[i] - g_first;
        if (lg != cur_lg) {
            if (cur_lg >= 0) {
                float* gp = lds_pool ? &gacc[cur_lg * 128 + sub * 8]
                                     : &gsum[(g_first + cur_lg) * 128 + sub * 8];
#pragma unroll
                for (int j = 0; j < 8; j++) atomicAdd(&gp[j], racc[j]);
#pragma unroll
                for (int j = 0; j < 8; j++) racc[j] = 0.f;
            }
            cur_lg = lg;
        }
        float di = dinv[i];
        uint4 su = hs4[(size_t)i * 16 + sub];
        float a0 = __uint_as_float(su.x << 16);
        float a1 = __uint_as_float(su.x & 0xffff0000u);
        float a2 = __uint_as_float(su.y << 16);
        float a3 = __uint_as_float(su.y & 0xffff0000u);
        float a4 = __uint_as_float(su.z << 16);
        float a5 = __uint_as_float(su.z & 0xffff0000u);
        float a6 = __uint_as_float(su.w << 16);
        float a7 = __uint_as_float(su.w & 0xffff0000u);
        int e = row_ptr[i], e1 = row_ptr[i + 1];
        for (; e + 7 < e1; e += 8) {
            int s0 = srcs[e],     s1 = srcs[e + 1], s2 = srcs[e + 2], s3 = srcs[e + 3];
            int s4 = srcs[e + 4], s5 = srcs[e + 5], s6 = srcs[e + 6], s7 = srcs[e + 7];
            uint4 u0 = hs4[(size_t)s0 * 16 + sub];
            uint4 u1 = hs4[(size_t)s1 * 16 + sub];
            uint4 u2 = hs4[(size_t)s2 * 16 + sub];
            uint4 u3 = hs4[(size_t)s3 * 16 + sub];
            uint4 u4 = hs4[(size_t)s4 * 16 + sub];
            uint4 u5 = hs4[(size_t)s5 * 16 + sub];
            uint4 u6 = hs4[(size_t)s6 * 16 + sub];
            uint4 u7 = hs4[(size_t)s7 * 16 + sub];
            ACC8(u0) ACC8(u1) ACC8(u2) ACC8(u3)
            ACC8(u4) ACC8(u5) ACC8(u6) ACC8(u7)
        }
        for (; e + 3 < e1; e += 4) {
            int s0 = srcs[e], s1 = srcs[e + 1], s2 = srcs[e + 2], s3 = srcs[e + 3];
            uint4 u0 = hs4[(size_t)s0 * 16 + sub];
            uint4 u1 = hs4[(size_t)s1 * 16 + sub];
            uint4 u2 = hs4[(size_t)s2 * 16 + sub];
            uint4 u3 = hs4[(size_t)s3 * 16 + sub];
            ACC8(u0) ACC8(u1) ACC8(u2) ACC8(u3)
        }
        for (; e < e1; ++e) {
            uint4 u0 = hs4[(size_t)srcs[e] * 16 + sub];
            ACC8(u0)
        }
        racc[0] += fmaxf(fmaf(a0, di, bb0.x), 0.f);
        racc[1] += fmaxf(fmaf(a1, di, bb0.y), 0.f);
        racc[2] += fmaxf(fmaf(a2, di, bb0.z), 0.f);
        racc[3] += fmaxf(fmaf(a3, di, bb0.w), 0.f);
        racc[4] += fmaxf(fmaf(a4, di, bb1.x), 0.f);
        racc[5] += fmaxf(fmaf(a5, di, bb1.y), 0.f);
        racc[6] += fmaxf(fmaf(a6, di, bb1.z), 0.f);
        racc[7] += fmaxf(fmaf(a7, di, bb1.w), 0.f);
    }
    if (cur_lg >= 0) {
        float* gp = lds_pool ? &gacc[cur_lg * 128 + sub * 8]
                             : &gsum[(g_first + cur_lg) * 128 + sub * 8];
#pragma unroll
        for (int j = 0; j < 8; j++) atomicAdd(&gp[j], racc[j]);
    }
    __syncthreads();
    for (int idx = tid; idx < slots * 128; idx += 256) {
        float v = gacc[idx];
        if (v != 0.f)
            atomicAdd(&gsum[(g_first + (idx >> 7)) * 128 + (idx & 127)], v);
    }
}

__device__ inline int lbound(const int* __restrict__ a, int n, int key) {
    int lo = 0, hi = n;
    while (lo < hi) {
        int mid = (lo + hi) >> 1;
        if (a[mid] < key) lo = mid + 1;
        else hi = mid;
    }
    return lo;
}

// ---------------- K7: head (mean, fc1 + relu, actor softmax, critic) -------
__global__ __launch_bounds__(64) void k_head(const float* __restrict__ gsum,
                                             const int* __restrict__ batch,
                                             const float* __restrict__ fc1_w,
                                             const float* __restrict__ fc1_b,
                                             const float* __restrict__ actor_w,
                                             const float* __restrict__ actor_b,
                                             const float* __restrict__ critic_w,
                                             const float* __restrict__ critic_b,
                                             float* __restrict__ out) {
    __shared__ float gs[128];
    __shared__ float zs[64];
    __shared__ float ls[8], es[8];
    int g = blockIdx.x, t = threadIdx.x;
    int lo = lbound(batch, NN, g), hi = lbound(batch, NN, g + 1);
    float invc = 1.f / fmaxf((float)(hi - lo), 1.f);
    gs[t] = gsum[g * 128 + t] * invc;
    gs[t + 64] = gsum[g * 128 + 64 + t] * invc;
    __syncthreads();
    float z = fc1_b[t];
    for (int k = 0; k < 128; k++) z = fmaf(gs[k], fc1_w[k * 64 + t], z);
    zs[t] = fmaxf(z, 0.f);
    __syncthreads();
    if (t < 8) {
        float l = actor_b[t];
        for (int k = 0; k < 64; k++) l = fmaf(zs[k], actor_w[k * 8 + t], l);
        ls[t] = l;
    }
    __syncthreads();
    if (t < 8) {
        float m = ls[0];
#pragma unroll
        for (int j = 1; j < 8; j++) m = fmaxf(m, ls[j]);
        es[t] = expf(ls[t] - m);
    }
    __syncthreads();
    if (t < 8) {
        float ssum = 0.f;
#pragma unroll
        for (int j = 0; j < 8; j++) ssum += es[j];
        out[g * 8 + t] = es[t] / ssum;
    }
    if (t == 32) {
        float v = critic_b[0];
        for (int k = 0; k < 64; k++) v = fmaf(zs[k], critic_w[k], v);
        out[GG * TT + g] = v;
    }
}

extern "C" void kernel_launch(void* const* d_in, const int* in_sizes, int n_in,
                              void* d_out, int out_size, void* d_ws, size_t ws_size,
                              hipStream_t stream) {
    const float* x        = (const float*)d_in[0];
    const int*   ei       = (const int*)d_in[1];
    const int*   batch    = (const int*)d_in[2];
    const float* W        = (const float*)d_in[3];
    const float* b        = (const float*)d_in[4];
    const float* fc1_w    = (const float*)d_in[5];
    const float* fc1_b    = (const float*)d_in[6];
    const float* actor_w  = (const float*)d_in[7];
    const float* actor_b  = (const float*)d_in[8];
    const float* critic_w = (const float*)d_in[9];
    const float* critic_b = (const float*)d_in[10];
    float* out = (float*)d_out;

    char* ws = (char*)d_ws;
    size_t off = 0;
    unsigned short* hs    = (unsigned short*)(ws + off); off += (size_t)NN * 128 * 2 + 64;  // 12.8 MB
    unsigned short* wt_bf = (unsigned short*)(ws + off); off += (size_t)128 * 128 * 2;      // 32 KB
    float* dinv      = (float*)(ws + off);    off += (size_t)NN * 4;
    int*   row_ptr   = (int*)(ws + off);      off += (size_t)(NN + 1) * 4 + 12;
    int*   srcs      = (int*)(ws + off);      off += (size_t)EE * 4;       // 3.2 MB
    unsigned* etmp   = (unsigned*)(ws + off); off += (size_t)EE * 4;       // 3.2 MB
    int*   table     = (int*)(ws + off);      off += (size_t)NSB * NB * 4; // 200 KB
    int*   bbase     = (int*)(ws + off);      off += (size_t)(NB + 1) * 4 + 12;
    int*   ctot      = (int*)(ws + off);      off += (size_t)NB * 4 + 16;
    float* gsum      = (float*)(ws + off);    off += (size_t)GG * HH * 4;

    const int* src = ei;        // edge_index[0]
    const int* dst = ei + EE;   // edge_index[1]

    k_front<<<NSB, 256, 0, stream>>>(dst, W, table, wt_bf, gsum);
    kb2a<<<NB, 256, 0, stream>>>(table, ctot);
    kb2b<<<1, 256, 0, stream>>>(ctot, bbase);
    kb3<<<NSB, 256, 0, stream>>>(src, dst, table, bbase, etmp);
    k_csr<<<NB, 256, 0, stream>>>(etmp, bbase, row_ptr, dinv, srcs);
    k_gemm<<<NPAD / 64, 256, 0, stream>>>(x, wt_bf, dinv, hs);
    k_aggr<<<(NN + 31) / 32, 256, 0, stream>>>((const uint4*)hs, row_ptr, srcs,
                                               dinv, b, batch, gsum);
    k_head<<<GG, 64, 0, stream>>>(gsum, batch, fc1_w, fc1_b, actor_w, actor_b,
                                  critic_w, critic_b, out);
}